// Round 4
// baseline (159.394 us; speedup 1.0000x reference)
//
#include <hip/hip_runtime.h>
#include <stdint.h>

// ---------------------------------------------------------------------------
// HeteNet round 6: local sort, expert-range (te-outer) MFMA loops with
// scalar guards -> weights hoisted once per (te, ks).
// Algebraic deletions: L1 ks=2 (gp cols + bias) folded into accumulator init
// via a token-uniform gfrag MFMA; L2 bias folded in via one-hot frag MFMA;
// xs stride shrunk to 72 (no pad columns).
// Kernels: prep -> main. ws holds wp (130 KiB).
// ---------------------------------------------------------------------------

typedef float v4f __attribute__((ext_vector_type(4)));
typedef short v8s __attribute__((ext_vector_type(8)));
typedef short v4s __attribute__((ext_vector_type(4)));
typedef float v4fa __attribute__((ext_vector_type(4), aligned(4)));

#define XS_STR 72      // LDS x stride (elems), 144 B = 9 x 16B -> read groups spread
#define HS_STR 136     // LDS h stride (elems), 272 B = 17 x 16B
#define WP2_OFF  30720 // 60 frag-blocks * 512 shorts
#define WP3_OFF  51200 // + 40 * 512
#define WPB2_OFF 56320 // + 10 * 512 ; L2-bias frags: 20 blocks

#define SEL4(te, a0, a1, a2, a3) \
    ((te) < 2 ? ((te) == 0 ? (a0) : (a1)) : ((te) == 2 ? (a2) : (a3)))

static __device__ __forceinline__ short f2bf(float f) {
    union { __bf16 b; short s; } u;
    u.b = (__bf16)f;   // native RNE convert
    return u.s;
}

static __device__ __forceinline__ v4s pack4r(const v4f a) {
    v4s r;
    r[0] = f2bf(fmaxf(a[0], 0.f));
    r[1] = f2bf(fmaxf(a[1], 0.f));
    r[2] = f2bf(fmaxf(a[2], 0.f));
    r[3] = f2bf(fmaxf(a[3], 0.f));
    return r;
}

// ---------------- weight prep: fragment-ready bf16 layout ----------------
// Frag-block = 512 shorts: lane l holds out-feat n=l&15, k=(l>>4)*8+j.
// L1 frags carry bias at k==68 (multiplied by gfrag's 1.0 slot).
// WPB2 region: L2 bias frags, nonzero only at local k==0 (one-hot onef).
__global__ void prep_kernel(const float* __restrict__ W1, const float* __restrict__ cW1,
                            const float* __restrict__ W2, const float* __restrict__ cW2,
                            const float* __restrict__ W3, const float* __restrict__ cW3,
                            const float* __restrict__ b1, const float* __restrict__ cb1,
                            const float* __restrict__ b2, const float* __restrict__ cb2,
                            short* __restrict__ wp) {
    int b = blockIdx.x, lane = threadIdx.x;
    int nl = lane & 15, quad = lane >> 4;
    short frag[8];
    if (b < 60) {
        int e = b / 12, rem = b % 12, ks = rem / 4, nt = rem % 4;
        int n = nt * 16 + nl;
#pragma unroll
        for (int j = 0; j < 8; j++) {
            int k = ks * 32 + quad * 8 + j;
            float v = 0.f;
            if (k < 68)       v = (e < 4) ? W1[(e * 68 + k) * 64 + n] : cW1[k * 64 + n];
            else if (k == 68) v = (e < 4) ? b1[e * 64 + n] : cb1[n];
            frag[j] = f2bf(v);
        }
    } else if (b < 100) {
        int u = b - 60, e = u / 8, ks = (u % 8) / 4, nt = u % 4;
        int n = nt * 16 + nl;
#pragma unroll
        for (int j = 0; j < 8; j++) {
            int k = ks * 32 + quad * 8 + j;
            frag[j] = f2bf((e < 4) ? W2[(e * 64 + k) * 64 + n] : cW2[k * 64 + n]);
        }
    } else if (b < 110) {
        int u = b - 100;
#pragma unroll
        for (int j = 0; j < 8; j++) {
            int ks = (u < 8) ? (u & 1) : (u - 8);
            int k  = ks * 32 + quad * 8 + j;
            float v;
            if (u < 8) { int ee = u >> 1; v = W3[(ee * 64 + k) * 16 + nl]; }
            else       { v = (nl == 0) ? cW3[k] : 0.f; }
            frag[j] = f2bf(v);
        }
    } else {
        // L2 bias frags: block = (net*4 + nt), value only at local k==0
        int u = b - 110, net = u / 4, nt = u % 4;
        int n = nt * 16 + nl;
#pragma unroll
        for (int j = 0; j < 8; j++) {
            float v = 0.f;
            if (quad == 0 && j == 0) v = (net < 4) ? b2[net * 64 + n] : cb2[n];
            frag[j] = f2bf(v);
        }
    }
    v8s pk = { frag[0], frag[1], frag[2], frag[3], frag[4], frag[5], frag[6], frag[7] };
    *(v8s*)(wp + (size_t)b * 512 + lane * 8) = pk;
}

// ---------------- fused main kernel ----------------

__global__ __launch_bounds__(256, 4) void main_kernel(
    const float* __restrict__ obs, const int* __restrict__ hete,
    const float* __restrict__ gp, const short* __restrict__ wp,
    const float* __restrict__ b3, const float* __restrict__ cb3,
    float* __restrict__ out)
{
    // union buffer: xs phase uses stride XS_STR (18432 B of it), hs phase
    // stride HS_STR (34816 B). Phases barrier-separated.
    __shared__ __align__(16) short buf[128 * HS_STR];
    __shared__ int rowtok[128];   // sorted row -> local token
    __shared__ int tslot[128];    // local token -> sorted row
    __shared__ int wcnt[2][4];    // per-wave expert counts

    short* xs = buf;
    short* hs = buf;

    const int b = blockIdx.x;
    const int tid = threadIdx.x, lane = tid & 63, w = tid >> 6;
    const int ml = lane & 15, quad = lane >> 4;
    const size_t base = (size_t)b * 128;

    // --- issue obs loads immediately (coalesced contiguous 32 KB/block) ---
    const int ltk = tid >> 1, hh = tid & 1;   // 2 threads per token, 32 floats each
    const float4* src = (const float4*)(obs + (base + ltk) * 64 + hh * 32);
    float4 f[8];
#pragma unroll
    for (int t = 0; t < 8; t++) f[t] = src[t];

    // gp row is block-uniform (one timestep per block)
    const float* gpb = gp + (size_t)b * 4;
    float g0 = gpb[0], g1 = gpb[1], g2 = gpb[2], g3 = gpb[3];

    // --- 4-way stable partition of 128 tokens (waves 0,1), NO padding ---
    int e = 0, rank = 0;
    if (tid < 128) {
        e = hete[base + tid];
        unsigned long long ltm = (1ull << lane) - 1ull;
        unsigned long long m0 = __ballot(e == 0);
        unsigned long long m1 = __ballot(e == 1);
        unsigned long long m2 = __ballot(e == 2);
        unsigned long long m3 = __ballot(e == 3);
        if      (e == 0) rank = __popcll(m0 & ltm);
        else if (e == 1) rank = __popcll(m1 & ltm);
        else if (e == 2) rank = __popcll(m2 & ltm);
        else             rank = __popcll(m3 & ltm);
        if (lane == 0) {
            wcnt[w][0] = __popcll(m0); wcnt[w][1] = __popcll(m1);
            wcnt[w][2] = __popcll(m2); wcnt[w][3] = __popcll(m3);
        }
    }
    __syncthreads();

    // group starts -> uniform scalars
    const int c0 = wcnt[0][0] + wcnt[1][0];
    const int c1 = wcnt[0][1] + wcnt[1][1];
    const int c2 = wcnt[0][2] + wcnt[1][2];
    const int sgs1 = __builtin_amdgcn_readfirstlane(c0);
    const int sgs2 = __builtin_amdgcn_readfirstlane(c0 + c1);
    const int sgs3 = __builtin_amdgcn_readfirstlane(c0 + c1 + c2);
    const int SG[5] = { 0, sgs1, sgs2, sgs3, 128 };

    if (tid < 128) {
        int gsE  = SEL4(e, 0, sgs1, sgs2, sgs3);
        int woff = (w == 1) ? wcnt[0][e] : 0;
        int slot = gsE + woff + rank;
        rowtok[slot] = tid;
        tslot[tid]   = slot;
    }
    __syncthreads();

    // --- stage x tile (sorted rows): obs cols 0..63 only ---
    {
        int s  = tslot[ltk];
        int rb = s * XS_STR + hh * 32;
#pragma unroll
        for (int t = 0; t < 4; t++) {
            float4 a0 = f[2 * t], a1 = f[2 * t + 1];
            v8s pk = { f2bf(a0.x), f2bf(a0.y), f2bf(a0.z), f2bf(a0.w),
                       f2bf(a1.x), f2bf(a1.y), f2bf(a1.z), f2bf(a1.w) };
            *(v8s*)&xs[rb + t * 8] = pk;
        }
    }

    // token-uniform B-frags (built in registers):
    // gfrag = x cols 64..95 (gp + 1.0 bias slot at k=68), onef = one-hot k=0
    v8s gfrag = (v8s){0,0,0,0,0,0,0,0};
    v8s onef  = (v8s){0,0,0,0,0,0,0,0};
    if (quad == 0) {
        gfrag[0] = f2bf(g0); gfrag[1] = f2bf(g1);
        gfrag[2] = f2bf(g2); gfrag[3] = f2bf(g3);
        gfrag[4] = (short)0x3F80;   // bf16 1.0 -> multiplies bias row k=68
        onef[0]  = (short)0x3F80;
    }
    __syncthreads();

    // =====================================================================
    // Layer 1: D = W^T X^T, K=96. ks=2 block (gp cols + bias) is
    // token-uniform -> one MFMA per net, used as accumulator INIT.
    // =====================================================================
    v4f accE[8], accC[8], fx[3];
#pragma unroll
    for (int mt = 0; mt < 8; mt++) { accE[mt] = (v4f){0,0,0,0}; }
    fx[0] = fx[1] = fx[2] = (v4f){0,0,0,0};

    {   // critic init (ks=2 + cb1)
        v8s cW2 = *(const v8s*)(wp + (size_t)(14 * 4 + w) * 512 + lane * 8); // (4*3+2)
        v4f tC = __builtin_amdgcn_mfma_f32_16x16x32_bf16(cW2, gfrag, (v4f){0,0,0,0}, 0, 0, 0);
#pragma unroll
        for (int mt = 0; mt < 8; mt++) accC[mt] = tC;
    }
#pragma unroll
    for (int te = 0; te < 4; te++) {
        int lo = SG[te], hi = SG[te + 1];
        if (lo < hi) {
            v8s aW2 = *(const v8s*)(wp + (size_t)((te * 3 + 2) * 4 + w) * 512 + lane * 8);
            v4f tE = __builtin_amdgcn_mfma_f32_16x16x32_bf16(aW2, gfrag, (v4f){0,0,0,0}, 0, 0, 0);
#pragma unroll
            for (int mt = 0; mt < 8; mt++)
                if (mt * 16 >= lo && mt * 16 < hi) accE[mt] = tE;
            if (te > 0 && (lo & 15)) fx[te - 1] = tE;
        }
    }

    v8s cf1[2];
#pragma unroll
    for (int ks = 0; ks < 2; ks++)
        cf1[ks] = *(const v8s*)(wp + (size_t)((12 + ks) * 4 + w) * 512 + lane * 8);

#pragma unroll
    for (int ks = 0; ks < 2; ks++) {
        // critic: all 8 tiles
#pragma unroll
        for (int mt = 0; mt < 8; mt++) {
            v8s xb = *(const v8s*)&xs[(mt * 16 + ml) * XS_STR + ks * 32 + quad * 8];
            accC[mt] = __builtin_amdgcn_mfma_f32_16x16x32_bf16(cf1[ks], xb, accC[mt], 0, 0, 0);
        }
        // experts: weights hoisted per (te, ks); scalar range guards
#pragma unroll
        for (int te = 0; te < 4; te++) {
            int lo = SG[te], hi = SG[te + 1];
            if (lo < hi) {
                v8s aW = *(const v8s*)(wp + (size_t)((te * 3 + ks) * 4 + w) * 512 + lane * 8);
#pragma unroll
                for (int mt = 0; mt < 8; mt++) {
                    if (mt * 16 >= lo && mt * 16 < hi) {
                        v8s xb = *(const v8s*)&xs[(mt * 16 + ml) * XS_STR + ks * 32 + quad * 8];
                        accE[mt] = __builtin_amdgcn_mfma_f32_16x16x32_bf16(aW, xb, accE[mt], 0, 0, 0);
                    }
                    if (te > 0 && (lo & 15) && (lo >> 4) == mt) {
                        v8s xb = *(const v8s*)&xs[(mt * 16 + ml) * XS_STR + ks * 32 + quad * 8];
                        fx[te - 1] = __builtin_amdgcn_mfma_f32_16x16x32_bf16(aW, xb, fx[te - 1], 0, 0, 0);
                    }
                }
            }
        }
    }
    __syncthreads();  // all xs reads complete before hs overwrites (union)

    // h1 writes (bias already in acc): packed b64
    {
#pragma unroll
        for (int mt = 0; mt < 8; mt++) {
            int rb = (mt * 16 + ml) * HS_STR + w * 16 + quad * 4;
            *(v4s*)&hs[rb]      = pack4r(accE[mt]);
            *(v4s*)&hs[rb + 64] = pack4r(accC[mt]);
        }
#pragma unroll
        for (int bb = 0; bb < 3; bb++) {
            int lo = SG[bb + 1], hi = SG[bb + 2];
            if ((lo & 15) && lo < hi) {
                int row  = (lo >> 4) * 16 + ml;
                int erow = (row >= sgs1) + (row >= sgs2) + (row >= sgs3);
                if (erow == bb + 1)
                    *(v4s*)&hs[row * HS_STR + w * 16 + quad * 4] = pack4r(fx[bb]);
            }
        }
    }
    __syncthreads();

    // =====================================================================
    // Layer 2: K=64 (2 ks); bias folded in via one-hot frag MFMA init.
    // =====================================================================
    v4f acc2E[8], acc2C[8], fx2[3];
#pragma unroll
    for (int mt = 0; mt < 8; mt++) { acc2E[mt] = (v4f){0,0,0,0}; }
    fx2[0] = fx2[1] = fx2[2] = (v4f){0,0,0,0};

    {   // critic bias init
        v8s cbf = *(const v8s*)(wp + WPB2_OFF + (size_t)(16 + w) * 512 + lane * 8);
        v4f tC = __builtin_amdgcn_mfma_f32_16x16x32_bf16(cbf, onef, (v4f){0,0,0,0}, 0, 0, 0);
#pragma unroll
        for (int mt = 0; mt < 8; mt++) acc2C[mt] = tC;
    }
#pragma unroll
    for (int te = 0; te < 4; te++) {
        int lo = SG[te], hi = SG[te + 1];
        if (lo < hi) {
            v8s bf = *(const v8s*)(wp + WPB2_OFF + (size_t)(te * 4 + w) * 512 + lane * 8);
            v4f tE = __builtin_amdgcn_mfma_f32_16x16x32_bf16(bf, onef, (v4f){0,0,0,0}, 0, 0, 0);
#pragma unroll
            for (int mt = 0; mt < 8; mt++)
                if (mt * 16 >= lo && mt * 16 < hi) acc2E[mt] = tE;
            if (te > 0 && (lo & 15)) fx2[te - 1] = tE;
        }
    }

    v8s cf2[2];
#pragma unroll
    for (int ks = 0; ks < 2; ks++)
        cf2[ks] = *(const v8s*)(wp + WP2_OFF + (size_t)((8 + ks) * 4 + w) * 512 + lane * 8);

#pragma unroll
    for (int ks = 0; ks < 2; ks++) {
#pragma unroll
        for (int mt = 0; mt < 8; mt++) {
            v8s hC = *(const v8s*)&hs[(mt * 16 + ml) * HS_STR + 64 + ks * 32 + quad * 8];
            acc2C[mt] = __builtin_amdgcn_mfma_f32_16x16x32_bf16(cf2[ks], hC, acc2C[mt], 0, 0, 0);
        }
#pragma unroll
        for (int te = 0; te < 4; te++) {
            int lo = SG[te], hi = SG[te + 1];
            if (lo < hi) {
                v8s aW = *(const v8s*)(wp + WP2_OFF + (size_t)((te * 2 + ks) * 4 + w) * 512 + lane * 8);
#pragma unroll
                for (int mt = 0; mt < 8; mt++) {
                    if (mt * 16 >= lo && mt * 16 < hi) {
                        v8s hE = *(const v8s*)&hs[(mt * 16 + ml) * HS_STR + ks * 32 + quad * 8];
                        acc2E[mt] = __builtin_amdgcn_mfma_f32_16x16x32_bf16(aW, hE, acc2E[mt], 0, 0, 0);
                    }
                    if (te > 0 && (lo & 15) && (lo >> 4) == mt) {
                        v8s hE = *(const v8s*)&hs[(mt * 16 + ml) * HS_STR + ks * 32 + quad * 8];
                        fx2[te - 1] = __builtin_amdgcn_mfma_f32_16x16x32_bf16(aW, hE, fx2[te - 1], 0, 0, 0);
                    }
                }
            }
        }
    }
    __syncthreads();  // all h1 reads complete before h2 overwrites

    {
#pragma unroll
        for (int mt = 0; mt < 8; mt++) {
            int rb = (mt * 16 + ml) * HS_STR + w * 16 + quad * 4;
            *(v4s*)&hs[rb]      = pack4r(acc2E[mt]);
            *(v4s*)&hs[rb + 64] = pack4r(acc2C[mt]);
        }
#pragma unroll
        for (int bb = 0; bb < 3; bb++) {
            int lo = SG[bb + 1], hi = SG[bb + 2];
            if ((lo & 15) && lo < hi) {
                int row  = (lo >> 4) * 16 + ml;
                int erow = (row >= sgs1) + (row >= sgs2) + (row >= sgs3);
                if (erow == bb + 1)
                    *(v4s*)&hs[row * HS_STR + w * 16 + quad * 4] = pack4r(fx2[bb]);
            }
        }
    }
    __syncthreads();

    // =====================================================================
    // Layer 3: wave w owns tiles {w, w+4}. M=16 logits; critic via padded M.
    // =====================================================================
    v4f accL[2], accV[2];
#pragma unroll
    for (int j = 0; j < 2; j++) { accL[j] = (v4f){0,0,0,0}; accV[j] = (v4f){0,0,0,0}; }

#pragma unroll
    for (int ks = 0; ks < 2; ks++) {
        v8s aV = *(const v8s*)(wp + WP3_OFF + (size_t)(8 + ks) * 512 + lane * 8);
#pragma unroll
        for (int j = 0; j < 2; j++) {
            int mt = w + 4 * j;
            int te = (mt * 16 >= sgs1) + (mt * 16 >= sgs2) + (mt * 16 >= sgs3);
            v8s aW = *(const v8s*)(wp + WP3_OFF + (size_t)(te * 2 + ks) * 512 + lane * 8);
            v8s hE = *(const v8s*)&hs[(mt * 16 + ml) * HS_STR + ks * 32 + quad * 8];
            v8s hC = *(const v8s*)&hs[(mt * 16 + ml) * HS_STR + 64 + ks * 32 + quad * 8];
            accL[j] = __builtin_amdgcn_mfma_f32_16x16x32_bf16(aW, hE, accL[j], 0, 0, 0);
            accV[j] = __builtin_amdgcn_mfma_f32_16x16x32_bf16(aV, hC, accV[j], 0, 0, 0);
        }
    }

    v4f fxL[3];
#pragma unroll
    for (int bb = 0; bb < 3; bb++) {
        fxL[bb] = (v4f){0,0,0,0};
        int lo = SG[bb + 1], hi = SG[bb + 2];
        int mtb = lo >> 4;
        if ((lo & 15) && lo < hi && (mtb & 3) == w) {
#pragma unroll
            for (int ks = 0; ks < 2; ks++) {
                v8s aW = *(const v8s*)(wp + WP3_OFF + (size_t)((bb + 1) * 2 + ks) * 512 + lane * 8);
                v8s hE = *(const v8s*)&hs[(mtb * 16 + ml) * HS_STR + ks * 32 + quad * 8];
                fxL[bb] = __builtin_amdgcn_mfma_f32_16x16x32_bf16(aW, hE, fxL[bb], 0, 0, 0);
            }
        }
    }

    // --- epilogue: dwordx4 logits store + value. Base store predicated on
    //     erow==te; fix-up is the sole writer for straddled tokens. ---
    {
        float cb3v = cb3[0];
#pragma unroll
        for (int j = 0; j < 2; j++) {
            int mt = w + 4 * j;
            int te = (mt * 16 >= sgs1) + (mt * 16 >= sgs2) + (mt * 16 >= sgs3);
            int row = mt * 16 + ml;
            int erow = (row >= sgs1) + (row >= sgs2) + (row >= sgs3);
            int tk = rowtok[row];
            float* o = out + (base + (size_t)tk) * 17;
            if (erow == te) {
                v4fa b3v = *(const v4fa*)(b3 + te * 16 + quad * 4);
                v4fa ov = { accL[j][0] + b3v[0], accL[j][1] + b3v[1],
                            accL[j][2] + b3v[2], accL[j][3] + b3v[3] };
                *(v4fa*)(o + quad * 4) = ov;
            }
            if (quad == 0) o[16] = accV[j][0] + cb3v;
        }
#pragma unroll
        for (int bb = 0; bb < 3; bb++) {
            int lo = SG[bb + 1], hi = SG[bb + 2];
            int mtb = lo >> 4;
            if ((lo & 15) && lo < hi && (mtb & 3) == w) {
                int row = mtb * 16 + ml;
                int erow = (row >= sgs1) + (row >= sgs2) + (row >= sgs3);
                if (erow == bb + 1) {
                    v4fa b3v = *(const v4fa*)(b3 + (bb + 1) * 16 + quad * 4);
                    int tk = rowtok[row];
                    float* o = out + (base + (size_t)tk) * 17;
                    v4fa ov = { fxL[bb][0] + b3v[0], fxL[bb][1] + b3v[1],
                                fxL[bb][2] + b3v[2], fxL[bb][3] + b3v[3] };
                    *(v4fa*)(o + quad * 4) = ov;
                }
            }
        }
    }
}

// ---------------------------------------------------------------------------

extern "C" void kernel_launch(void* const* d_in, const int* in_sizes, int n_in,
                              void* d_out, int out_size, void* d_ws, size_t ws_size,
                              hipStream_t stream) {
    const float* obs = (const float*)d_in[0];
    const int*  hete = (const int*)d_in[1];
    const float* gp  = (const float*)d_in[2];
    const float* W1  = (const float*)d_in[3];
    const float* b1  = (const float*)d_in[4];
    const float* W2  = (const float*)d_in[5];
    const float* b2  = (const float*)d_in[6];
    const float* W3  = (const float*)d_in[7];
    const float* b3  = (const float*)d_in[8];
    const float* cW1 = (const float*)d_in[9];
    const float* cb1 = (const float*)d_in[10];
    const float* cW2 = (const float*)d_in[11];
    const float* cb2 = (const float*)d_in[12];
    const float* cW3 = (const float*)d_in[13];
    const float* cb3 = (const float*)d_in[14];
    float* out = (float*)d_out;

    short* wp = (short*)d_ws;   // 130 * 512 shorts = 133120 B

    prep_kernel<<<130,  64, 0, stream>>>(W1, cW1, W2, cW2, W3, cW3,
                                         b1, cb1, b2, cb2, wp);
    main_kernel<<<2048, 256, 0, stream>>>(obs, hete, gp, wp, b3, cb3, out);
}